// Round 1
// baseline (677.298 us; speedup 1.0000x reference)
//
#include <hip/hip_runtime.h>
#include <hip/hip_bf16.h>
#include <cstdint>

#define N_ROWS 4096
#define N_CLS  8192
#define D_EMB  512
#define K_DIM  1024   // 2*D_EMB

using bf16x8 = __attribute__((ext_vector_type(8))) short;
using f32x4  = __attribute__((ext_vector_type(4))) float;

__device__ __forceinline__ float bf2f(unsigned short u) {
  return __uint_as_float(((unsigned int)u) << 16);
}

__device__ __forceinline__ unsigned short f2bf(float f) {
  unsigned int x = __float_as_uint(f);
  unsigned int lsb = (x >> 16) & 1u;
  x += 0x7fffu + lsb;            // round-to-nearest-even
  return (unsigned short)(x >> 16);
}

// block-wide sum for 256 threads (4 waves); re-entrant (syncs guard the LDS)
__device__ __forceinline__ float block_sum256(float v) {
  __shared__ float red[4];
  #pragma unroll
  for (int o = 32; o; o >>= 1) v += __shfl_xor(v, o);
  __syncthreads();
  if ((threadIdx.x & 63) == 0) red[threadIdx.x >> 6] = v;
  __syncthreads();
  return red[0] + red[1] + red[2] + red[3];
}

__device__ __forceinline__ void global_to_lds16(const void* g, void* l) {
  const __attribute__((address_space(1))) unsigned int* gp =
      reinterpret_cast<const __attribute__((address_space(1))) unsigned int*>(
          reinterpret_cast<uintptr_t>(g));
  __attribute__((address_space(3))) unsigned int* lp =
      reinterpret_cast<__attribute__((address_space(3))) unsigned int*>(
          reinterpret_cast<uintptr_t>(l));
  __builtin_amdgcn_global_load_lds(gp, lp, 16, 0, 0);
}

// ---------------------------------------------------------------------------
// K1: per-class prep. Bmat[c, 0:512] = s_c (bf16), Bmat[c, 512:1024] = (P*s)_c.
//     tvec[c] = sum_d P^2 s ;  klc[c] = sum_d 0.5*(1/s + pn^2 - 1 + log s)
// ---------------------------------------------------------------------------
__global__ __launch_bounds__(256) void k_proxy(const float* __restrict__ proxies,
                                               const float* __restrict__ sigmas_inv,
                                               unsigned short* __restrict__ Bmat,
                                               float* __restrict__ tvec,
                                               float* __restrict__ klc) {
  const int c = blockIdx.x;
  const int tid = threadIdx.x;
  const float* p  = proxies    + (size_t)c * D_EMB;
  const float* si = sigmas_inv + (size_t)c * D_EMB;
  float p0 = p[tid], p1 = p[tid + 256];
  float ss = block_sum256(p0 * p0 + p1 * p1);
  float invn = 1.0f / fmaxf(sqrtf(ss), 1e-12f);
  unsigned short* brow = Bmat + (size_t)c * K_DIM;
  float tc = 0.f, kl = 0.f;
  #pragma unroll
  for (int e = 0; e < 2; ++e) {
    int d = tid + e * 256;
    float pv = (e ? p1 : p0);
    float sv = si[d];
    float sp = (sv > 20.f) ? sv : log1pf(expf(sv));   // softplus
    float s  = sp * sp;
    float pn = pv * invn;
    float P  = 3.0f * pn;
    brow[d]          = f2bf(s);
    brow[D_EMB + d]  = f2bf(P * s);
    tc += P * P * s;
    kl += 0.5f * (1.0f / s + pn * pn - 1.0f + 2.0f * logf(sp));
  }
  tc = block_sum256(tc);
  kl = block_sum256(kl);
  if (tid == 0) { tvec[c] = tc; klc[c] = kl; }
}

// ---------------------------------------------------------------------------
// K2: per-row prep. Amat[n, 0:512] = -Xn^2 (bf16), Amat[n, 512:1024] = 2*Xn.
// ---------------------------------------------------------------------------
__global__ __launch_bounds__(256) void k_xprep(const float* __restrict__ X,
                                               unsigned short* __restrict__ Amat) {
  const int n = blockIdx.x;
  const int tid = threadIdx.x;
  const float* x = X + (size_t)n * D_EMB;
  float x0 = x[tid], x1 = x[tid + 256];
  float ss = block_sum256(x0 * x0 + x1 * x1);
  float invn = 3.0f / fmaxf(sqrtf(ss), 1e-12f);   // SCALE folded in
  unsigned short* arow = Amat + (size_t)n * K_DIM;
  #pragma unroll
  for (int e = 0; e < 2; ++e) {
    int d = tid + e * 256;
    float xv = (e ? x1 : x0) * invn;              // Xn
    arow[d]         = f2bf(-(xv * xv));
    arow[D_EMB + d] = f2bf(2.0f * xv);
  }
}

// ---------------------------------------------------------------------------
// K3: 128x128-tile bf16 MFMA GEMM (K=1024) fused with per-tile row max/sumexp.
//     z[n,c] = A[n]·B[c] - t_c ; writes Pm/Psum[n, col_tile].
// ---------------------------------------------------------------------------
__global__ __launch_bounds__(256) void k_gemm_lse(const unsigned short* __restrict__ Amat,
                                                  const unsigned short* __restrict__ Bmat,
                                                  const float* __restrict__ tvec,
                                                  float* __restrict__ Pm,
                                                  float* __restrict__ Psum) {
  union SMem {
    struct { unsigned short As[128 * 64]; unsigned short Bs[128 * 64]; } st;
    float zt[128 * 129];
  };
  __shared__ SMem sm;
  const int tid  = threadIdx.x;
  const int lane = tid & 63;
  const int wave = tid >> 6;
  const int wr = wave >> 1, wc = wave & 1;          // 2x2 wave grid, 64x64 each
  const int row0 = blockIdx.x * 128;
  const int col0 = blockIdx.y * 128;

  f32x4 acc[4][4];
  #pragma unroll
  for (int i = 0; i < 4; ++i)
    #pragma unroll
    for (int j = 0; j < 4; ++j) acc[i][j] = (f32x4){0.f, 0.f, 0.f, 0.f};

  for (int ko = 0; ko < K_DIM; ko += 64) {
    #pragma unroll
    for (int rep = 0; rep < 4; ++rep) {
      int flat = rep * 2048 + tid * 8;              // 8 bf16 = 16B per lane
      int r  = flat >> 6;
      int kk = flat & 63;
      const unsigned short* ga = Amat + ((size_t)(row0 + r)) * K_DIM + ko + kk;
      const unsigned short* gb = Bmat + ((size_t)(col0 + r)) * K_DIM + ko + kk;
      global_to_lds16(ga, &sm.st.As[flat]);
      global_to_lds16(gb, &sm.st.Bs[flat]);
    }
    __syncthreads();
    #pragma unroll
    for (int ks = 0; ks < 64; ks += 32) {
      bf16x8 af[4], bfr[4];
      #pragma unroll
      for (int mi = 0; mi < 4; ++mi) {
        int row = wr * 64 + mi * 16 + (lane & 15);
        int k   = ks + (lane >> 4) * 8;
        af[mi] = *(const bf16x8*)&sm.st.As[row * 64 + k];
      }
      #pragma unroll
      for (int ni = 0; ni < 4; ++ni) {
        int col = wc * 64 + ni * 16 + (lane & 15);
        int k   = ks + (lane >> 4) * 8;
        bfr[ni] = *(const bf16x8*)&sm.st.Bs[col * 64 + k];
      }
      #pragma unroll
      for (int mi = 0; mi < 4; ++mi)
        #pragma unroll
        for (int ni = 0; ni < 4; ++ni)
          acc[mi][ni] = __builtin_amdgcn_mfma_f32_16x16x32_bf16(af[mi], bfr[ni], acc[mi][ni], 0, 0, 0);
    }
    __syncthreads();
  }

  // epilogue: z = acc - t[col]; spill to LDS (pad 129 to dodge bank conflicts)
  #pragma unroll
  for (int mi = 0; mi < 4; ++mi) {
    int rbase = wr * 64 + mi * 16 + ((lane >> 4) << 2);
    #pragma unroll
    for (int ni = 0; ni < 4; ++ni) {
      int col = wc * 64 + ni * 16 + (lane & 15);
      float tc = tvec[col0 + col];
      #pragma unroll
      for (int j = 0; j < 4; ++j)
        sm.zt[(rbase + j) * 129 + col] = acc[mi][ni][j] - tc;
    }
  }
  __syncthreads();
  {
    int row  = tid >> 1;
    int half = tid & 1;
    const float* zr = &sm.zt[row * 129 + half * 64];
    float m = -3.0e38f;
    #pragma unroll 8
    for (int i = 0; i < 64; ++i) m = fmaxf(m, zr[i]);
    m = fmaxf(m, __shfl_xor(m, 1));
    float s = 0.f;
    #pragma unroll 8
    for (int i = 0; i < 64; ++i) s += __expf(zr[i] - m);
    s += __shfl_xor(s, 1);
    if (half == 0) {
      Pm  [(size_t)(row0 + row) * 64 + blockIdx.y] = m;
      Psum[(size_t)(row0 + row) * 64 + blockIdx.y] = s;
    }
  }
}

// ---------------------------------------------------------------------------
// K4: exact target logit per row: tgt[n] = A[n]·B[T[n]] - t[T[n]]
// ---------------------------------------------------------------------------
__global__ __launch_bounds__(256) void k_target(const unsigned short* __restrict__ Amat,
                                                const unsigned short* __restrict__ Bmat,
                                                const float* __restrict__ tvec,
                                                const int* __restrict__ T,
                                                float* __restrict__ tgt) {
  const int lane = threadIdx.x & 63;
  const int n = blockIdx.x * 4 + (threadIdx.x >> 6);
  const int c = T[n];
  const unsigned short* a = Amat + (size_t)n * K_DIM + lane * 16;
  const unsigned short* b = Bmat + (size_t)c * K_DIM + lane * 16;
  float s = 0.f;
  #pragma unroll
  for (int i = 0; i < 16; ++i) s += bf2f(a[i]) * bf2f(b[i]);
  #pragma unroll
  for (int o = 32; o; o >>= 1) s += __shfl_xor(s, o);
  if (lane == 0) tgt[n] = s - tvec[c];
}

// ---------------------------------------------------------------------------
// K5: single-block deterministic combine: LSE over 64 partials/row, ce + KL.
// ---------------------------------------------------------------------------
__global__ __launch_bounds__(256) void k_final(const float* __restrict__ Pm,
                                               const float* __restrict__ Psum,
                                               const float* __restrict__ tgt,
                                               const float* __restrict__ klc,
                                               float* __restrict__ out) {
  const int tid = threadIdx.x;
  float kls = 0.f;
  for (int c = tid; c < N_CLS; c += 256) kls += klc[c];
  float ces = 0.f;
  for (int n = tid; n < N_ROWS; n += 256) {
    const float* pm = Pm   + (size_t)n * 64;
    const float* ps = Psum + (size_t)n * 64;
    float m = -3.0e38f;
    #pragma unroll 8
    for (int i = 0; i < 64; ++i) m = fmaxf(m, pm[i]);
    float S = 0.f;
    #pragma unroll 8
    for (int i = 0; i < 64; ++i) S += ps[i] * __expf(pm[i] - m);
    ces += (m + logf(S)) - tgt[n];
  }
  kls = block_sum256(kls);
  ces = block_sum256(ces);
  if (tid == 0) out[0] = ces / (float)N_ROWS + 0.2f * (kls / (float)N_CLS);
}

extern "C" void kernel_launch(void* const* d_in, const int* in_sizes, int n_in,
                              void* d_out, int out_size, void* d_ws, size_t ws_size,
                              hipStream_t stream) {
  const float* X          = (const float*)d_in[0];
  // d_in[1] = indices (unused by the reference loss)
  const int*   T          = (const int*)d_in[2];
  const float* proxies    = (const float*)d_in[3];
  const float* sigmas_inv = (const float*)d_in[4];

  char* ws = (char*)d_ws;
  unsigned short* Amat = (unsigned short*)ws;                          // 8 MiB
  unsigned short* Bmat = (unsigned short*)(ws + (8u << 20));           // 16 MiB
  float* tvec = (float*)(ws + (24u << 20));                            // 32 KiB
  float* klc  = (float*)(ws + (24u << 20) + (32u << 10));              // 32 KiB
  float* Pm   = (float*)(ws + (24u << 20) + (64u << 10));              // 1 MiB
  float* Psum = (float*)(ws + (25u << 20) + (64u << 10));              // 1 MiB
  float* tgt  = (float*)(ws + (26u << 20) + (64u << 10));              // 16 KiB
  float* out  = (float*)d_out;

  hipLaunchKernelGGL(k_proxy,    dim3(N_CLS),      dim3(256), 0, stream, proxies, sigmas_inv, Bmat, tvec, klc);
  hipLaunchKernelGGL(k_xprep,    dim3(N_ROWS),     dim3(256), 0, stream, X, Amat);
  hipLaunchKernelGGL(k_gemm_lse, dim3(32, 64),     dim3(256), 0, stream, Amat, Bmat, tvec, Pm, Psum);
  hipLaunchKernelGGL(k_target,   dim3(N_ROWS / 4), dim3(256), 0, stream, Amat, Bmat, tvec, T, tgt);
  hipLaunchKernelGGL(k_final,    dim3(1),          dim3(256), 0, stream, Pm, Psum, tgt, klc, out);
}

// Round 2
// 172.343 us; speedup vs baseline: 3.9299x; 3.9299x over previous
//
#include <hip/hip_runtime.h>
#include <hip/hip_bf16.h>
#include <cstdint>

#define N_ROWS 4096
#define N_CLS  8192
#define D_EMB  512
#define K_DIM  1024   // 2*D_EMB

using bf16x8 = __attribute__((ext_vector_type(8))) short;
using f32x4  = __attribute__((ext_vector_type(4))) float;

__device__ __forceinline__ float bf2f(unsigned short u) {
  return __uint_as_float(((unsigned int)u) << 16);
}

__device__ __forceinline__ unsigned short f2bf(float f) {
  unsigned int x = __float_as_uint(f);
  unsigned int lsb = (x >> 16) & 1u;
  x += 0x7fffu + lsb;            // round-to-nearest-even
  return (unsigned short)(x >> 16);
}

// block-wide sum for 256 threads (4 waves); re-entrant (syncs guard the LDS)
__device__ __forceinline__ float block_sum256(float v) {
  __shared__ float red[4];
  #pragma unroll
  for (int o = 32; o; o >>= 1) v += __shfl_xor(v, o);
  __syncthreads();
  if ((threadIdx.x & 63) == 0) red[threadIdx.x >> 6] = v;
  __syncthreads();
  return red[0] + red[1] + red[2] + red[3];
}

__device__ __forceinline__ void global_to_lds16(const void* g, void* l) {
  const __attribute__((address_space(1))) unsigned int* gp =
      reinterpret_cast<const __attribute__((address_space(1))) unsigned int*>(
          reinterpret_cast<uintptr_t>(g));
  __attribute__((address_space(3))) unsigned int* lp =
      reinterpret_cast<__attribute__((address_space(3))) unsigned int*>(
          reinterpret_cast<uintptr_t>(l));
  __builtin_amdgcn_global_load_lds(gp, lp, 16, 0, 0);
}

// ---------------------------------------------------------------------------
// K1: per-class prep. Bmat[c, 0:512] = s_c (bf16), Bmat[c, 512:1024] = (P*s)_c.
//     tvec[c] = sum_d P^2 s ;  klc[c] = sum_d 0.5*(1/s + pn^2 - 1 + log s)
// ---------------------------------------------------------------------------
__global__ __launch_bounds__(256) void k_proxy(const float* __restrict__ proxies,
                                               const float* __restrict__ sigmas_inv,
                                               unsigned short* __restrict__ Bmat,
                                               float* __restrict__ tvec,
                                               float* __restrict__ klc) {
  const int c = blockIdx.x;
  const int tid = threadIdx.x;
  const float* p  = proxies    + (size_t)c * D_EMB;
  const float* si = sigmas_inv + (size_t)c * D_EMB;
  float p0 = p[tid], p1 = p[tid + 256];
  float ss = block_sum256(p0 * p0 + p1 * p1);
  float invn = 1.0f / fmaxf(sqrtf(ss), 1e-12f);
  unsigned short* brow = Bmat + (size_t)c * K_DIM;
  float tc = 0.f, kl = 0.f;
  #pragma unroll
  for (int e = 0; e < 2; ++e) {
    int d = tid + e * 256;
    float pv = (e ? p1 : p0);
    float sv = si[d];
    float sp = (sv > 20.f) ? sv : log1pf(expf(sv));   // softplus
    float s  = sp * sp;
    float pn = pv * invn;
    float P  = 3.0f * pn;
    brow[d]          = f2bf(s);
    brow[D_EMB + d]  = f2bf(P * s);
    tc += P * P * s;
    kl += 0.5f * (1.0f / s + pn * pn - 1.0f + 2.0f * logf(sp));
  }
  tc = block_sum256(tc);
  kl = block_sum256(kl);
  if (tid == 0) { tvec[c] = tc; klc[c] = kl; }
}

// ---------------------------------------------------------------------------
// K2: per-row prep. Amat[n, 0:512] = -Xn^2 (bf16), Amat[n, 512:1024] = 2*Xn.
// ---------------------------------------------------------------------------
__global__ __launch_bounds__(256) void k_xprep(const float* __restrict__ X,
                                               unsigned short* __restrict__ Amat) {
  const int n = blockIdx.x;
  const int tid = threadIdx.x;
  const float* x = X + (size_t)n * D_EMB;
  float x0 = x[tid], x1 = x[tid + 256];
  float ss = block_sum256(x0 * x0 + x1 * x1);
  float invn = 3.0f / fmaxf(sqrtf(ss), 1e-12f);   // SCALE folded in
  unsigned short* arow = Amat + (size_t)n * K_DIM;
  #pragma unroll
  for (int e = 0; e < 2; ++e) {
    int d = tid + e * 256;
    float xv = (e ? x1 : x0) * invn;              // Xn
    arow[d]         = f2bf(-(xv * xv));
    arow[D_EMB + d] = f2bf(2.0f * xv);
  }
}

// ---------------------------------------------------------------------------
// K3: 128x128-tile bf16 MFMA GEMM (K=1024) fused with per-row max/sumexp.
//     LDS tiles XOR-swizzled (T2): logical (row, kbyte) stored at
//     kbyte ^ ((row&7)<<4). global_load_lds dest stays LINEAR; the source
//     global address carries the inverse swizzle (involution).
// ---------------------------------------------------------------------------
__global__ __launch_bounds__(256) void k_gemm_lse(const unsigned short* __restrict__ Amat,
                                                  const unsigned short* __restrict__ Bmat,
                                                  const float* __restrict__ tvec,
                                                  float* __restrict__ Pm,
                                                  float* __restrict__ Psum) {
  union SMem {
    struct { unsigned short As[128 * 64]; unsigned short Bs[128 * 64]; } st; // 32 KB
    float ms[128][2][2];   // [row][wc][{m,s}] epilogue combine (reuses staging LDS)
  };
  __shared__ SMem sm;
  const int tid  = threadIdx.x;
  const int lane = tid & 63;
  const int wave = tid >> 6;
  const int wr = wave >> 1, wc = wave & 1;          // 2x2 wave grid, 64x64 each
  const int row0 = blockIdx.x * 128;
  const int col0 = blockIdx.y * 128;

  f32x4 acc[4][4];
  #pragma unroll
  for (int i = 0; i < 4; ++i)
    #pragma unroll
    for (int j = 0; j < 4; ++j) acc[i][j] = (f32x4){0.f, 0.f, 0.f, 0.f};

  for (int ko = 0; ko < K_DIM; ko += 64) {
    #pragma unroll
    for (int rep = 0; rep < 4; ++rep) {
      int flat = rep * 2048 + tid * 8;              // dest bf16 idx (LINEAR in LDS)
      int r  = flat >> 6;
      int kk = flat & 63;
      int kk_src = kk ^ ((r & 7) << 3);             // inverse swizzle on SOURCE
      const unsigned short* ga = Amat + ((size_t)(row0 + r)) * K_DIM + ko + kk_src;
      const unsigned short* gb = Bmat + ((size_t)(col0 + r)) * K_DIM + ko + kk_src;
      global_to_lds16(ga, &sm.st.As[flat]);
      global_to_lds16(gb, &sm.st.Bs[flat]);
    }
    __syncthreads();
    #pragma unroll
    for (int ks = 0; ks < 64; ks += 32) {
      bf16x8 af[4], bfr[4];
      #pragma unroll
      for (int mi = 0; mi < 4; ++mi) {
        int row = wr * 64 + mi * 16 + (lane & 15);
        int k   = ks + (lane >> 4) * 8;
        int ksw = k ^ ((row & 7) << 3);             // swizzled read
        af[mi] = *(const bf16x8*)&sm.st.As[row * 64 + ksw];
      }
      #pragma unroll
      for (int ni = 0; ni < 4; ++ni) {
        int col = wc * 64 + ni * 16 + (lane & 15);
        int k   = ks + (lane >> 4) * 8;
        int ksw = k ^ ((col & 7) << 3);
        bfr[ni] = *(const bf16x8*)&sm.st.Bs[col * 64 + ksw];
      }
      #pragma unroll
      for (int mi = 0; mi < 4; ++mi)
        #pragma unroll
        for (int ni = 0; ni < 4; ++ni)
          acc[mi][ni] = __builtin_amdgcn_mfma_f32_16x16x32_bf16(af[mi], bfr[ni], acc[mi][ni], 0, 0, 0);
    }
    __syncthreads();
  }

  // ---- in-register epilogue: per-row max / sumexp over this wave's 64 cols.
  // C/D layout: col = lane&15 (within 16-col frag), row = (lane>>4)*4 + j.
  float tc[4];
  #pragma unroll
  for (int ni = 0; ni < 4; ++ni)
    tc[ni] = tvec[col0 + wc * 64 + ni * 16 + (lane & 15)];

  // staging LDS no longer needed (all ds_reads precede the final barrier)
  #pragma unroll
  for (int mi = 0; mi < 4; ++mi) {
    #pragma unroll
    for (int j = 0; j < 4; ++j) {
      float z0 = acc[mi][0][j] - tc[0];
      float z1 = acc[mi][1][j] - tc[1];
      float z2 = acc[mi][2][j] - tc[2];
      float z3 = acc[mi][3][j] - tc[3];
      float m = fmaxf(fmaxf(z0, z1), fmaxf(z2, z3));
      #pragma unroll
      for (int o = 1; o < 16; o <<= 1) m = fmaxf(m, __shfl_xor(m, o));
      float s = __expf(z0 - m) + __expf(z1 - m) + __expf(z2 - m) + __expf(z3 - m);
      #pragma unroll
      for (int o = 1; o < 16; o <<= 1) s += __shfl_xor(s, o);
      if ((lane & 15) == 0) {
        int rloc = wr * 64 + mi * 16 + ((lane >> 4) << 2) + j;
        sm.ms[rloc][wc][0] = m;
        sm.ms[rloc][wc][1] = s;
      }
    }
  }
  __syncthreads();
  if (tid < 128) {
    float m0 = sm.ms[tid][0][0], s0 = sm.ms[tid][0][1];
    float m1 = sm.ms[tid][1][0], s1 = sm.ms[tid][1][1];
    float M = fmaxf(m0, m1);
    float S = s0 * __expf(m0 - M) + s1 * __expf(m1 - M);
    Pm  [(size_t)(row0 + tid) * 64 + blockIdx.y] = M;
    Psum[(size_t)(row0 + tid) * 64 + blockIdx.y] = S;
  }
}

// ---------------------------------------------------------------------------
// K4: exact target logit per row: tgt[n] = A[n]·B[T[n]] - t[T[n]]
// ---------------------------------------------------------------------------
__global__ __launch_bounds__(256) void k_target(const unsigned short* __restrict__ Amat,
                                                const unsigned short* __restrict__ Bmat,
                                                const float* __restrict__ tvec,
                                                const int* __restrict__ T,
                                                float* __restrict__ tgt) {
  const int lane = threadIdx.x & 63;
  const int n = blockIdx.x * 4 + (threadIdx.x >> 6);
  const int c = T[n];
  const unsigned short* a = Amat + (size_t)n * K_DIM + lane * 16;
  const unsigned short* b = Bmat + (size_t)c * K_DIM + lane * 16;
  float s = 0.f;
  #pragma unroll
  for (int i = 0; i < 16; ++i) s += bf2f(a[i]) * bf2f(b[i]);
  #pragma unroll
  for (int o = 32; o; o >>= 1) s += __shfl_xor(s, o);
  if (lane == 0) tgt[n] = s - tvec[c];
}

// ---------------------------------------------------------------------------
// K5a: 64-block reduce. Block b: rows [b*64, b*64+64) -> ce partial;
//      classes [b*128, b*128+128) -> kl partial.
// ---------------------------------------------------------------------------
__global__ __launch_bounds__(256) void k_red(const float* __restrict__ Pm,
                                             const float* __restrict__ Psum,
                                             const float* __restrict__ tgt,
                                             const float* __restrict__ klc,
                                             float* __restrict__ cep,
                                             float* __restrict__ klp) {
  const int b = blockIdx.x;
  const int tid = threadIdx.x;
  const int n = b * 64 + (tid >> 2);
  const int q = tid & 3;
  const float4* pm4 = (const float4*)(Pm   + (size_t)n * 64 + q * 16);
  const float4* ps4 = (const float4*)(Psum + (size_t)n * 64 + q * 16);
  float4 pm[4], ps[4];
  #pragma unroll
  for (int i = 0; i < 4; ++i) { pm[i] = pm4[i]; ps[i] = ps4[i]; }
  float m = -3.0e38f;
  #pragma unroll
  for (int i = 0; i < 4; ++i)
    m = fmaxf(m, fmaxf(fmaxf(pm[i].x, pm[i].y), fmaxf(pm[i].z, pm[i].w)));
  m = fmaxf(m, __shfl_xor(m, 1));
  m = fmaxf(m, __shfl_xor(m, 2));
  float S = 0.f;
  #pragma unroll
  for (int i = 0; i < 4; ++i) {
    S += ps[i].x * __expf(pm[i].x - m) + ps[i].y * __expf(pm[i].y - m)
       + ps[i].z * __expf(pm[i].z - m) + ps[i].w * __expf(pm[i].w - m);
  }
  S += __shfl_xor(S, 1);
  S += __shfl_xor(S, 2);
  float ce = (q == 0) ? (m + logf(S) - tgt[n]) : 0.f;
  float kl = (tid < 128) ? klc[b * 128 + tid] : 0.f;
  ce = block_sum256(ce);
  kl = block_sum256(kl);
  if (tid == 0) { cep[b] = ce; klp[b] = kl; }
}

// K5b: final combine (1 block, 64 threads)
__global__ __launch_bounds__(64) void k_fin2(const float* __restrict__ cep,
                                             const float* __restrict__ klp,
                                             float* __restrict__ out) {
  const int tid = threadIdx.x;
  float ce = cep[tid], kl = klp[tid];
  #pragma unroll
  for (int o = 32; o; o >>= 1) { ce += __shfl_xor(ce, o); kl += __shfl_xor(kl, o); }
  if (tid == 0) out[0] = ce / (float)N_ROWS + 0.2f * (kl / (float)N_CLS);
}

extern "C" void kernel_launch(void* const* d_in, const int* in_sizes, int n_in,
                              void* d_out, int out_size, void* d_ws, size_t ws_size,
                              hipStream_t stream) {
  const float* X          = (const float*)d_in[0];
  // d_in[1] = indices (unused by the reference loss)
  const int*   T          = (const int*)d_in[2];
  const float* proxies    = (const float*)d_in[3];
  const float* sigmas_inv = (const float*)d_in[4];

  char* ws = (char*)d_ws;
  unsigned short* Amat = (unsigned short*)ws;                          // 8 MiB
  unsigned short* Bmat = (unsigned short*)(ws + (8u << 20));           // 16 MiB
  float* tvec = (float*)(ws + (24u << 20));                            // 32 KiB
  float* klc  = (float*)(ws + (24u << 20) + (32u << 10));              // 32 KiB
  float* Pm   = (float*)(ws + (24u << 20) + (64u << 10));              // 1 MiB
  float* Psum = (float*)(ws + (25u << 20) + (64u << 10));              // 1 MiB
  float* tgt  = (float*)(ws + (26u << 20) + (64u << 10));              // 16 KiB
  float* cep  = (float*)(ws + (26u << 20) + (128u << 10));             // 256 B
  float* klp  = (float*)(ws + (26u << 20) + (132u << 10));             // 256 B
  float* out  = (float*)d_out;

  hipLaunchKernelGGL(k_proxy,    dim3(N_CLS),      dim3(256), 0, stream, proxies, sigmas_inv, Bmat, tvec, klc);
  hipLaunchKernelGGL(k_xprep,    dim3(N_ROWS),     dim3(256), 0, stream, X, Amat);
  hipLaunchKernelGGL(k_gemm_lse, dim3(32, 64),     dim3(256), 0, stream, Amat, Bmat, tvec, Pm, Psum);
  hipLaunchKernelGGL(k_target,   dim3(N_ROWS / 4), dim3(256), 0, stream, Amat, Bmat, tvec, T, tgt);
  hipLaunchKernelGGL(k_red,      dim3(64),         dim3(256), 0, stream, Pm, Psum, tgt, klc, cep, klp);
  hipLaunchKernelGGL(k_fin2,     dim3(1),          dim3(64),  0, stream, cep, klp, out);
}

// Round 3
// 111.427 us; speedup vs baseline: 6.0784x; 1.5467x over previous
//
#include <hip/hip_runtime.h>
#include <hip/hip_bf16.h>
#include <cstdint>

#define N_ROWS 4096
#define N_CLS  8192
#define D_EMB  512
#define K_DIM  1024   // 2*D_EMB

using bf16x8 = __attribute__((ext_vector_type(8))) short;
using f32x4  = __attribute__((ext_vector_type(4))) float;

__device__ __forceinline__ float bf2f(unsigned short u) {
  return __uint_as_float(((unsigned int)u) << 16);
}

__device__ __forceinline__ unsigned short f2bf(float f) {
  unsigned int x = __float_as_uint(f);
  unsigned int lsb = (x >> 16) & 1u;
  x += 0x7fffu + lsb;            // round-to-nearest-even
  return (unsigned short)(x >> 16);
}

// block-wide sum for 256 threads (4 waves); re-entrant (syncs guard the LDS)
__device__ __forceinline__ float block_sum256(float v) {
  __shared__ float red[4];
  #pragma unroll
  for (int o = 32; o; o >>= 1) v += __shfl_xor(v, o);
  __syncthreads();
  if ((threadIdx.x & 63) == 0) red[threadIdx.x >> 6] = v;
  __syncthreads();
  return red[0] + red[1] + red[2] + red[3];
}

__device__ __forceinline__ void global_to_lds16(const void* g, void* l) {
  const __attribute__((address_space(1))) unsigned int* gp =
      reinterpret_cast<const __attribute__((address_space(1))) unsigned int*>(
          reinterpret_cast<uintptr_t>(g));
  __attribute__((address_space(3))) unsigned int* lp =
      reinterpret_cast<__attribute__((address_space(3))) unsigned int*>(
          reinterpret_cast<uintptr_t>(l));
  __builtin_amdgcn_global_load_lds(gp, lp, 16, 0, 0);
}

// ---------------------------------------------------------------------------
// K1: per-class prep. Bmat[c, 0:512] = s_c (bf16), Bmat[c, 512:1024] = (P*s)_c.
//     tvec[c] = sum_d P^2 s ;  klc[c] = sum_d 0.5*(1/s + pn^2 - 1 + log s)
// ---------------------------------------------------------------------------
__global__ __launch_bounds__(256) void k_proxy(const float* __restrict__ proxies,
                                               const float* __restrict__ sigmas_inv,
                                               unsigned short* __restrict__ Bmat,
                                               float* __restrict__ tvec,
                                               float* __restrict__ klc) {
  const int c = blockIdx.x;
  const int tid = threadIdx.x;
  const float* p  = proxies    + (size_t)c * D_EMB;
  const float* si = sigmas_inv + (size_t)c * D_EMB;
  float p0 = p[tid], p1 = p[tid + 256];
  float ss = block_sum256(p0 * p0 + p1 * p1);
  float invn = 1.0f / fmaxf(sqrtf(ss), 1e-12f);
  unsigned short* brow = Bmat + (size_t)c * K_DIM;
  float tc = 0.f, kl = 0.f;
  #pragma unroll
  for (int e = 0; e < 2; ++e) {
    int d = tid + e * 256;
    float pv = (e ? p1 : p0);
    float sv = si[d];
    float sp = (sv > 20.f) ? sv : log1pf(expf(sv));   // softplus
    float s  = sp * sp;
    float pn = pv * invn;
    float P  = 3.0f * pn;
    brow[d]          = f2bf(s);
    brow[D_EMB + d]  = f2bf(P * s);
    tc += P * P * s;
    kl += 0.5f * (1.0f / s + pn * pn - 1.0f + 2.0f * logf(sp));
  }
  tc = block_sum256(tc);
  kl = block_sum256(kl);
  if (tid == 0) { tvec[c] = tc; klc[c] = kl; }
}

// ---------------------------------------------------------------------------
// K2: per-row prep. Amat[n, 0:512] = -Xn^2 (bf16), Amat[n, 512:1024] = 2*Xn.
// ---------------------------------------------------------------------------
__global__ __launch_bounds__(256) void k_xprep(const float* __restrict__ X,
                                               unsigned short* __restrict__ Amat) {
  const int n = blockIdx.x;
  const int tid = threadIdx.x;
  const float* x = X + (size_t)n * D_EMB;
  float x0 = x[tid], x1 = x[tid + 256];
  float ss = block_sum256(x0 * x0 + x1 * x1);
  float invn = 3.0f / fmaxf(sqrtf(ss), 1e-12f);   // SCALE folded in
  unsigned short* arow = Amat + (size_t)n * K_DIM;
  #pragma unroll
  for (int e = 0; e < 2; ++e) {
    int d = tid + e * 256;
    float xv = (e ? x1 : x0) * invn;              // Xn
    arow[d]         = f2bf(-(xv * xv));
    arow[D_EMB + d] = f2bf(2.0f * xv);
  }
}

// ---------------------------------------------------------------------------
// K3: 256x256-tile bf16 MFMA GEMM (K=1024), double-buffered LDS with
//     prefetch-issue-before-compute (T3-minimum), T2 XOR swizzle, T1 XCD
//     chunked block swizzle, T5 setprio. Fused per-row max/sumexp epilogue.
//     8 waves (2M x 4N), per-wave output 128x64.
// ---------------------------------------------------------------------------
__global__ __launch_bounds__(512, 2) void k_gemm_lse(const unsigned short* __restrict__ Amat,
                                                     const unsigned short* __restrict__ Bmat,
                                                     const float* __restrict__ tvec,
                                                     float* __restrict__ Pm,
                                                     float* __restrict__ Psum) {
  union SMem {
    struct { unsigned short As[2][256 * 64]; unsigned short Bs[2][256 * 64]; } st; // 128 KB
    float ms[256][4][2];   // 8 KB epilogue combine; overlaps As[0] only (final tile uses buf 1)
  };
  __shared__ SMem sm;
  const int tid  = threadIdx.x;
  const int lane = tid & 63;
  const int wave = tid >> 6;
  const int wr = wave >> 2, wc = wave & 3;          // 2x4 wave grid; per-wave 128x64 out
  // T1: chunked XCD swizzle. nwg=512, 64 consecutive per XCD (bid%8 = XCD).
  const int swz  = ((int)blockIdx.x & 7) * 64 + ((int)blockIdx.x >> 3);
  const int row0 = (swz & 15) * 256;                // 16 row tiles
  const int cty  = swz >> 4;                        // 32 col tiles
  const int col0 = cty * 256;

  f32x4 acc[8][4];
  #pragma unroll
  for (int i = 0; i < 8; ++i)
    #pragma unroll
    for (int j = 0; j < 4; ++j) acc[i][j] = (f32x4){0.f, 0.f, 0.f, 0.f};

  const int arow  = wr * 128 + (lane & 15);         // + mi*16
  const int bcol  = wc * 64  + (lane & 15);         // + ni*16
  const int kbase = (lane >> 4) * 8;

  auto stage = [&](int buf, int ko) {
    #pragma unroll
    for (int rep = 0; rep < 4; ++rep) {
      int flat = rep * 4096 + tid * 8;              // LINEAR LDS dest (bf16 idx)
      int r  = flat >> 6;
      int kk = flat & 63;
      int kk_src = kk ^ ((r & 7) << 3);             // inverse swizzle on SOURCE
      global_to_lds16(Amat + ((size_t)(row0 + r)) * K_DIM + ko + kk_src, &sm.st.As[buf][flat]);
      global_to_lds16(Bmat + ((size_t)(col0 + r)) * K_DIM + ko + kk_src, &sm.st.Bs[buf][flat]);
    }
  };

  stage(0, 0);
  __syncthreads();                                  // drains vmcnt(0): buf0 ready
  for (int t = 0; t < 16; ++t) {
    if (t < 15) stage((t + 1) & 1, (t + 1) * 64);   // issue next-tile loads FIRST
    const unsigned short* Ab = sm.st.As[t & 1];
    const unsigned short* Bb = sm.st.Bs[t & 1];
    __builtin_amdgcn_s_setprio(1);
    #pragma unroll
    for (int ks = 0; ks < 64; ks += 32) {
      bf16x8 af[8], bfr[4];
      #pragma unroll
      for (int mi = 0; mi < 8; ++mi) {
        int row = arow + mi * 16;
        int k   = ks + kbase;
        af[mi] = *(const bf16x8*)&Ab[row * 64 + (k ^ ((row & 7) << 3))];
      }
      #pragma unroll
      for (int ni = 0; ni < 4; ++ni) {
        int col = bcol + ni * 16;
        int k   = ks + kbase;
        bfr[ni] = *(const bf16x8*)&Bb[col * 64 + (k ^ ((col & 7) << 3))];
      }
      #pragma unroll
      for (int mi = 0; mi < 8; ++mi)
        #pragma unroll
        for (int ni = 0; ni < 4; ++ni)
          acc[mi][ni] = __builtin_amdgcn_mfma_f32_16x16x32_bf16(af[mi], bfr[ni], acc[mi][ni], 0, 0, 0);
    }
    __builtin_amdgcn_s_setprio(0);
    __syncthreads();   // drains vmcnt(0) AFTER compute: prefetch latency hidden
  }

  // ---- in-register epilogue: per-row max / sumexp over this wave's 64 cols.
  // C/D layout: col = lane&15, row = (lane>>4)*4 + j.
  float tc[4];
  #pragma unroll
  for (int ni = 0; ni < 4; ++ni)
    tc[ni] = tvec[col0 + wc * 64 + ni * 16 + (lane & 15)];

  #pragma unroll
  for (int mi = 0; mi < 8; ++mi) {
    #pragma unroll
    for (int j = 0; j < 4; ++j) {
      float z0 = acc[mi][0][j] - tc[0];
      float z1 = acc[mi][1][j] - tc[1];
      float z2 = acc[mi][2][j] - tc[2];
      float z3 = acc[mi][3][j] - tc[3];
      float m = fmaxf(fmaxf(z0, z1), fmaxf(z2, z3));
      #pragma unroll
      for (int o = 1; o < 16; o <<= 1) m = fmaxf(m, __shfl_xor(m, o));
      float s = __expf(z0 - m) + __expf(z1 - m) + __expf(z2 - m) + __expf(z3 - m);
      #pragma unroll
      for (int o = 1; o < 16; o <<= 1) s += __shfl_xor(s, o);
      if ((lane & 15) == 0) {
        int rloc = wr * 128 + mi * 16 + ((lane >> 4) << 2) + j;
        sm.ms[rloc][wc][0] = m;
        sm.ms[rloc][wc][1] = s;
      }
    }
  }
  __syncthreads();
  if (tid < 256) {
    float m0 = sm.ms[tid][0][0], s0 = sm.ms[tid][0][1];
    float m1 = sm.ms[tid][1][0], s1 = sm.ms[tid][1][1];
    float m2 = sm.ms[tid][2][0], s2 = sm.ms[tid][2][1];
    float m3 = sm.ms[tid][3][0], s3 = sm.ms[tid][3][1];
    float M = fmaxf(fmaxf(m0, m1), fmaxf(m2, m3));
    float S = s0 * __expf(m0 - M) + s1 * __expf(m1 - M)
            + s2 * __expf(m2 - M) + s3 * __expf(m3 - M);
    Pm  [(size_t)(row0 + tid) * 32 + cty] = M;
    Psum[(size_t)(row0 + tid) * 32 + cty] = S;
  }
}

// ---------------------------------------------------------------------------
// K4: exact target logit per row: tgt[n] = A[n]·B[T[n]] - t[T[n]]
// ---------------------------------------------------------------------------
__global__ __launch_bounds__(256) void k_target(const unsigned short* __restrict__ Amat,
                                                const unsigned short* __restrict__ Bmat,
                                                const float* __restrict__ tvec,
                                                const int* __restrict__ T,
                                                float* __restrict__ tgt) {
  const int lane = threadIdx.x & 63;
  const int n = blockIdx.x * 4 + (threadIdx.x >> 6);
  const int c = T[n];
  const unsigned short* a = Amat + (size_t)n * K_DIM + lane * 16;
  const unsigned short* b = Bmat + (size_t)c * K_DIM + lane * 16;
  float s = 0.f;
  #pragma unroll
  for (int i = 0; i < 16; ++i) s += bf2f(a[i]) * bf2f(b[i]);
  #pragma unroll
  for (int o = 32; o; o >>= 1) s += __shfl_xor(s, o);
  if (lane == 0) tgt[n] = s - tvec[c];
}

// ---------------------------------------------------------------------------
// K5a: 64-block reduce. Block b: rows [b*64, b*64+64) -> ce partial;
//      classes [b*128, b*128+128) -> kl partial. 32 LSE partials per row.
// ---------------------------------------------------------------------------
__global__ __launch_bounds__(256) void k_red(const float* __restrict__ Pm,
                                             const float* __restrict__ Psum,
                                             const float* __restrict__ tgt,
                                             const float* __restrict__ klc,
                                             float* __restrict__ cep,
                                             float* __restrict__ klp) {
  const int b = blockIdx.x;
  const int tid = threadIdx.x;
  const int n = b * 64 + (tid >> 2);
  const int q = tid & 3;                            // 4 lanes/row, 8 floats each
  const float4* pm4 = (const float4*)(Pm   + (size_t)n * 32 + q * 8);
  const float4* ps4 = (const float4*)(Psum + (size_t)n * 32 + q * 8);
  float4 pm[2], ps[2];
  #pragma unroll
  for (int i = 0; i < 2; ++i) { pm[i] = pm4[i]; ps[i] = ps4[i]; }
  float m = -3.0e38f;
  #pragma unroll
  for (int i = 0; i < 2; ++i)
    m = fmaxf(m, fmaxf(fmaxf(pm[i].x, pm[i].y), fmaxf(pm[i].z, pm[i].w)));
  m = fmaxf(m, __shfl_xor(m, 1));
  m = fmaxf(m, __shfl_xor(m, 2));
  float S = 0.f;
  #pragma unroll
  for (int i = 0; i < 2; ++i) {
    S += ps[i].x * __expf(pm[i].x - m) + ps[i].y * __expf(pm[i].y - m)
       + ps[i].z * __expf(pm[i].z - m) + ps[i].w * __expf(pm[i].w - m);
  }
  S += __shfl_xor(S, 1);
  S += __shfl_xor(S, 2);
  float ce = (q == 0) ? (m + logf(S) - tgt[n]) : 0.f;
  float kl = (tid < 128) ? klc[b * 128 + tid] : 0.f;
  ce = block_sum256(ce);
  kl = block_sum256(kl);
  if (tid == 0) { cep[b] = ce; klp[b] = kl; }
}

// K5b: final combine (1 block, 64 threads)
__global__ __launch_bounds__(64) void k_fin2(const float* __restrict__ cep,
                                             const float* __restrict__ klp,
                                             float* __restrict__ out) {
  const int tid = threadIdx.x;
  float ce = cep[tid], kl = klp[tid];
  #pragma unroll
  for (int o = 32; o; o >>= 1) { ce += __shfl_xor(ce, o); kl += __shfl_xor(kl, o); }
  if (tid == 0) out[0] = ce / (float)N_ROWS + 0.2f * (kl / (float)N_CLS);
}

extern "C" void kernel_launch(void* const* d_in, const int* in_sizes, int n_in,
                              void* d_out, int out_size, void* d_ws, size_t ws_size,
                              hipStream_t stream) {
  const float* X          = (const float*)d_in[0];
  // d_in[1] = indices (unused by the reference loss)
  const int*   T          = (const int*)d_in[2];
  const float* proxies    = (const float*)d_in[3];
  const float* sigmas_inv = (const float*)d_in[4];

  char* ws = (char*)d_ws;
  unsigned short* Amat = (unsigned short*)ws;                          // 8 MiB
  unsigned short* Bmat = (unsigned short*)(ws + (8u << 20));           // 16 MiB
  float* tvec = (float*)(ws + (24u << 20));                            // 32 KiB
  float* klc  = (float*)(ws + (24u << 20) + (32u << 10));              // 32 KiB
  float* Pm   = (float*)(ws + (24u << 20) + (64u << 10));              // 512 KiB
  float* Psum = (float*)(ws + (24u << 20) + (576u << 10));             // 512 KiB
  float* tgt  = (float*)(ws + (24u << 20) + (1088u << 10));            // 16 KiB
  float* cep  = (float*)(ws + (24u << 20) + (1104u << 10));            // 256 B
  float* klp  = (float*)(ws + (24u << 20) + (1108u << 10));            // 256 B
  float* out  = (float*)d_out;

  hipLaunchKernelGGL(k_proxy,    dim3(N_CLS),      dim3(256), 0, stream, proxies, sigmas_inv, Bmat, tvec, klc);
  hipLaunchKernelGGL(k_xprep,    dim3(N_ROWS),     dim3(256), 0, stream, X, Amat);
  hipLaunchKernelGGL(k_gemm_lse, dim3(512),        dim3(512), 0, stream, Amat, Bmat, tvec, Pm, Psum);
  hipLaunchKernelGGL(k_target,   dim3(N_ROWS / 4), dim3(256), 0, stream, Amat, Bmat, tvec, T, tgt);
  hipLaunchKernelGGL(k_red,      dim3(64),         dim3(256), 0, stream, Pm, Psum, tgt, klc, cep, klp);
  hipLaunchKernelGGL(k_fin2,     dim3(1),          dim3(64),  0, stream, cep, klp, out);
}